// Round 4
// baseline (624.365 us; speedup 1.0000x reference)
//
#include <hip/hip_runtime.h>

#define NR    32768
#define NOBJ  16
#define NS    32
#define NB    64
#define WIDTH 576          // NB + NOBJ*NS
#define MISSV 1e10f

// ---- pinned fp32 ops: identical rounding everywhere ----
__device__ __forceinline__ float fmulr(float a, float b){ return __fmul_rn(a,b); }
__device__ __forceinline__ float faddr(float a, float b){ return __fadd_rn(a,b); }
__device__ __forceinline__ float fsubr(float a, float b){ return __fsub_rn(a,b); }
__device__ __forceinline__ float fdvr (float a, float b){ return __fdiv_rn(a,b); }

struct RayObj {
  float oo[3];   // ray origin in object frame
  float dd[3];   // normalized ray dir in object frame
  float t_in, dt;
  float dn;      // |d_w @ M3x3|  (object-t -> world-z divisor)
  bool  hit;
};

// Shared by both roles so hit/t_in/dt are bit-identical across them.
__device__ __forceinline__ void ray_obj_setup(
    const float* __restrict__ origins, const float* __restrict__ dirs,
    const float* __restrict__ trafos,  const float* __restrict__ scales,
    int m, int n, RayObj& R)
{
  const float o0 = origins[3*n+0], o1 = origins[3*n+1], o2 = origins[3*n+2];
  const float r0 = dirs[3*n+0],    r1 = dirs[3*n+1],    r2 = dirs[3*n+2];
  const float nn = __fsqrt_rn(faddr(faddr(fmulr(r0,r0), fmulr(r1,r1)), fmulr(r2,r2)));
  const float w0 = fdvr(r0,nn), w1 = fdvr(r1,nn), w2 = fdvr(r2,nn);

  const float* T = trafos + 16*m;
  const float* S = scales + 16*m;
  const float s0 = S[0], s1 = S[5], s2 = S[10];
  const float pm00 = fmulr(T[0],  s0), pm01 = fmulr(T[1],  s1), pm02 = fmulr(T[2],  s2);
  const float pm10 = fmulr(T[4],  s0), pm11 = fmulr(T[5],  s1), pm12 = fmulr(T[6],  s2);
  const float pm20 = fmulr(T[8],  s0), pm21 = fmulr(T[9],  s1), pm22 = fmulr(T[10], s2);
  const float tm0  = fmulr(T[12], s0), tm1  = fmulr(T[13], s1), tm2  = fmulr(T[14], s2);

  const float oo0 = faddr(faddr(faddr(fmulr(o0,pm00), fmulr(o1,pm10)), fmulr(o2,pm20)), tm0);
  const float oo1 = faddr(faddr(faddr(fmulr(o0,pm01), fmulr(o1,pm11)), fmulr(o2,pm21)), tm1);
  const float oo2 = faddr(faddr(faddr(fmulr(o0,pm02), fmulr(o1,pm12)), fmulr(o2,pm22)), tm2);
  const float du0 = faddr(faddr(fmulr(w0,pm00), fmulr(w1,pm10)), fmulr(w2,pm20));
  const float du1 = faddr(faddr(fmulr(w0,pm01), fmulr(w1,pm11)), fmulr(w2,pm21));
  const float du2 = faddr(faddr(fmulr(w0,pm02), fmulr(w1,pm12)), fmulr(w2,pm22));
  const float dn  = __fsqrt_rn(faddr(faddr(fmulr(du0,du0), fmulr(du1,du1)), fmulr(du2,du2)));
  const float dd0 = fdvr(du0,dn), dd1 = fdvr(du1,dn), dd2 = fdvr(du2,dn);

  const float i0 = fdvr(1.0f, dd0), i1 = fdvr(1.0f, dd1), i2 = fdvr(1.0f, dd2);
  const float a0 = fmulr(fsubr(-1.0f, oo0), i0), b0 = fmulr(fsubr(1.0f, oo0), i0);
  const float a1 = fmulr(fsubr(-1.0f, oo1), i1), b1 = fmulr(fsubr(1.0f, oo1), i1);
  const float a2 = fmulr(fsubr(-1.0f, oo2), i2), b2 = fmulr(fsubr(1.0f, oo2), i2);
  const float tmn = fmaxf(fmaxf(fminf(a0,b0), fminf(a1,b1)), fminf(a2,b2));
  const float tmx = fminf(fminf(fmaxf(a0,b0), fmaxf(a1,b1)), fmaxf(a2,b2));

  R.hit  = (tmx > tmn) && (tmx > 0.0f);
  R.t_in = fmaxf(tmn, 0.0f);
  R.dt   = fsubr(tmx, R.t_in);
  R.dn   = dn;
  R.oo[0]=oo0; R.oo[1]=oo1; R.oo[2]=oo2;
  R.dd[0]=dd0; R.dd[1]=dd1; R.dd[2]=dd2;
}

// count of elements in run m2 ordered before `key` (tie -> run m2 precedes)
__device__ __forceinline__ int count_run(const float* __restrict__ K,
                                         const float* __restrict__ A,
                                         const float* __restrict__ B,
                                         const float* __restrict__ IB,
                                         int m2, float key, bool tie)
{
  const float A2 = A[m2], B2 = B[m2];
  const float* V = K + NB + m2 * NS;
  if (B2 <= 0.0f) {  // degenerate run: all 32 keys equal A2
    return (A2 < key || (A2 == key && tie)) ? NS : 0;
  }
  float g = floorf(fmulr(fsubr(key, A2), IB[m2]));
  g = fminf(33.0f, fmaxf(-1.0f, g));
  int c = (int)g + 1;
  c = c < 0 ? 0 : (c > NS ? NS : c);
  while (c > 0)  { const float v = V[c-1]; if (v < key || (v == key && tie)) break; --c; }
  while (c < NS) { const float v = V[c];   if (v < key || (v == key && tie)) ++c; else break; }
  return c;
}

// Sort-role LDS: keys plane + params + ONE packed (key|node) plane.
// All keys >= 0 so float bit order == value order; low 5 mantissa bits carry
// node+1 (0=base/miss, 1..16=object). Key perturbation <= 31 ulp << threshold.
// 9216 + 768 + 9216 = 19200 B -> 8 blocks/CU (vs 28.4 KB / 5 blocks before).
struct SortS {
  float    sKeys[4][WIDTH];
  float    sA[4][NOBJ], sB[4][NOBJ], sIB[4][NOBJ];
  unsigned sP[4][WIDTH];
};

// ============ Fused kernel: even blocks write pts/dirs, odd blocks rank-sort ============
__global__ __launch_bounds__(256) void k_fused(
    const float* __restrict__ origins, const float* __restrict__ dirs,
    const float* __restrict__ lengths,
    const float* __restrict__ trafos,  const float* __restrict__ scales,
    float* __restrict__ outL, float* __restrict__ outN, float* __restrict__ outM,
    float* __restrict__ outP, float* __restrict__ outD)
{
  __shared__ SortS U;
  const int tid  = threadIdx.x;
  const int role = blockIdx.x & 1;
  const int bid  = blockIdx.x >> 1;
  const int wv   = tid >> 6;
  const int lane = tid & 63;

  if (role == 0) {
    // ---------------- pts/dirs writer: barrier-free, wave-owns-16-rays ----------------
    const int m  = bid >> 9;           // 16 objects
    const int n0 = (bid & 511) << 6;   // 512 chunks of 64 rays
    float p0=0.f,p1=0.f,p2=0.f,p3=0.f,p4=0.f,p5=0.f,p6=0.f,p7=0.f;
    if (lane < 16) {
      RayObj R;
      ray_obj_setup(origins, dirs, trafos, scales, m, n0 + 16*wv + lane, R);
      if (R.hit) {
        p0=R.oo[0]; p1=R.oo[1]; p2=R.oo[2];
        p3=R.dd[0]; p4=R.dd[1]; p5=R.dd[2];
        p6=R.t_in;  p7=R.dt;
      }
    }
    // wave w covers float4 window [384w, 384w+384) of the block's 1536
    float4* P4 = (float4*)(outP + (size_t)(m * NR + n0) * 96) + wv * 384;
    float4* D4 = (float4*)(outD + (size_t)(m * NR + n0) * 96) + wv * 384;
    #pragma unroll
    for (int it = 0; it < 6; ++it) {
      const int fw  = lane + (it << 6);   // lane-consecutive -> coalesced
      const int rl  = fw / 24;            // local ray 0..15 (24 float4 per ray)
      const int off = (fw - rl * 24) * 4;
      const float oox = __shfl(p0, rl), ooy = __shfl(p1, rl), ooz = __shfl(p2, rl);
      const float ddx = __shfl(p3, rl), ddy = __shfl(p4, rl), ddz = __shfl(p5, rl);
      const float ti  = __shfl(p6, rl), dtt = __shfl(p7, rl);
      float4 p, d;
      float* pp = (float*)&p; float* dv = (float*)&d;
      #pragma unroll
      for (int i = 0; i < 4; ++i) {
        const int idx = off + i;
        const int s   = idx / 3;
        const int c   = idx - s * 3;
        const float z  = ti + dtt * ((float)s * (1.0f/31.0f));
        const float oc = (c == 0) ? oox : ((c == 1) ? ooy : ooz);
        const float dc = (c == 0) ? ddx : ((c == 1) ? ddy : ddz);
        pp[i] = oc + dc * z;   // miss rays: all-zero params -> exact 0 output
        dv[i] = dc;
      }
      P4[fw] = p;
      D4[fw] = d;
    }
    return;
  }

  // ---------------- rank-sort (4 rays per block, one wave per ray) ----------------
  const int n = bid * 4 + wv;

  // phase A: lanes 0..15 compute per-object key-line params.
  // Exact identity: world z of object-t sample = t/dn (round-trip through o2w collapses).
  if (lane < NOBJ) {
    RayObj R;
    ray_obj_setup(origins, dirs, trafos, scales, lane, n, R);
    float myA = MISSV, myB = -1.0f, myIB = 0.0f;
    if (R.hit) {
      const double invdn = 1.0 / (double)R.dn;
      myA = (float)((double)R.t_in * invdn);
      myB = (float)(((double)R.dt * invdn) * (1.0 / 31.0));
      if (!(myB > 0.0f)) myB = 0.0f;
      myIB = (myB > 0.0f) ? (1.0f / myB) : 0.0f;
    }
    U.sA[wv][lane]  = myA;
    U.sB[wv][lane]  = R.hit ? myB : -1.0f;         // B<0 encodes miss
    U.sIB[wv][lane] = myIB;
  }
  __syncthreads();

  unsigned hm = 0;
  #pragma unroll
  for (int mm = 0; mm < NOBJ; ++mm) hm |= (U.sB[wv][mm] >= 0.0f ? 1u : 0u) << mm;
  const int H = __popc(hm);

  // phase B: generate 576 keys (element e = lane + 64k)
  float kr[9];
  kr[0] = lengths[n * NB + lane];
  U.sKeys[wv][lane] = kr[0];
  #pragma unroll
  for (int k = 1; k < 9; ++k) {
    const int m0 = 2*(k-1) + (lane >> 5);
    const int s  = lane & 31;
    const float A_ = U.sA[wv][m0], B_ = U.sB[wv][m0];
    const float key = (B_ < 0.0f) ? MISSV : faddr(A_, fmulr(B_, (float)s));
    kr[k] = key;
    U.sKeys[wv][64*k + lane] = key;
  }
  __syncthreads();

  // phase C: exact rank per element, scatter packed (key|node+1) into LDS
  const float* K = U.sKeys[wv];
  #pragma unroll
  for (int k = 0; k < 9; ++k) {
    const float key = kr[k];
    int rank; unsigned n5; float outkey = key;
    if (k == 0) {
      rank = lane;                                 // stable: base precedes all on ties
      unsigned mm = hm;
      while (mm) { const int m2 = __ffs(mm) - 1; mm &= mm - 1;
        rank += count_run(K, U.sA[wv], U.sB[wv], U.sIB[wv], m2, key, false); }
      n5 = 0u;
    } else {
      const int m = 2*(k-1) + (lane >> 5);
      const int s = lane & 31;
      if (!((hm >> m) & 1u)) {
        const int MB = __popc((~hm) & ((1u << m) - 1u) & 0xFFFFu);
        rank = NB + NS*H + NS*MB + s;              // closed-form tail rank
        n5 = 0u; outkey = MISSV;
      } else {
        rank = s;
        int c = 0;                                 // upper_bound over sorted base lengths
        #pragma unroll
        for (int st = 64; st >= 1; st >>= 1) {
          const int t2 = c + st;
          if (t2 <= NB && K[t2-1] <= key) c = t2;
        }
        rank += c;
        unsigned mm = hm & ~(1u << m);
        while (mm) { const int m2 = __ffs(mm) - 1; mm &= mm - 1;
          rank += count_run(K, U.sA[wv], U.sB[wv], U.sIB[wv], m2, key, m2 < m); }
        n5 = (unsigned)(m + 1);
      }
    }
    U.sP[wv][rank] = (__float_as_uint(outkey) & ~31u) | n5;
  }
  __syncthreads();

  // coalesced copy-out: 144 uint4 -> 3x float4 per iteration
  float4* pL = (float4*)(outL + (size_t)n * WIDTH);
  float4* pN = (float4*)(outN + (size_t)n * WIDTH);
  float4* pM = (float4*)(outM + (size_t)n * WIDTH);
  const uint4* qP = (const uint4*)U.sP[wv];
  for (int i = lane; i < WIDTH/4; i += 64) {
    const uint4 v = qP[i];
    float4 lv, nv, mv;
    const unsigned ax = v.x & 31u, ay = v.y & 31u, az = v.z & 31u, aw = v.w & 31u;
    lv.x = __uint_as_float(v.x & ~31u); lv.y = __uint_as_float(v.y & ~31u);
    lv.z = __uint_as_float(v.z & ~31u); lv.w = __uint_as_float(v.w & ~31u);
    nv.x = (float)(int)ax - 1.0f; nv.y = (float)(int)ay - 1.0f;
    nv.z = (float)(int)az - 1.0f; nv.w = (float)(int)aw - 1.0f;
    mv.x = ax ? 1.0f : 0.0f; mv.y = ay ? 1.0f : 0.0f;
    mv.z = az ? 1.0f : 0.0f; mv.w = aw ? 1.0f : 0.0f;
    pL[i] = lv;
    pN[i] = nv;
    pM[i] = mv;
  }
}

extern "C" void kernel_launch(void* const* d_in, const int* in_sizes, int n_in,
                              void* d_out, int out_size, void* d_ws, size_t ws_size,
                              hipStream_t stream)
{
  (void)in_sizes; (void)n_in; (void)out_size; (void)d_ws; (void)ws_size;
  const float* origins = (const float*)d_in[0];
  const float* dirs    = (const float*)d_in[1];
  const float* lengths = (const float*)d_in[2];
  const float* trafos  = (const float*)d_in[3];
  // d_in[4] = rots_w2o: its 3x3 equals trafos' 3x3 (dir transform) -> unused
  const float* scales  = (const float*)d_in[5];

  float* out  = (float*)d_out;
  float* outL = out;
  float* outN = out + (size_t)NR * WIDTH;
  float* outM = out + (size_t)2 * NR * WIDTH;
  float* outP = out + (size_t)3 * NR * WIDTH;
  float* outD = outP + (size_t)NOBJ * NR * NS * 3;

  // even blocks: 8192 pts-writer tiles; odd blocks: 8192 sort blocks (4 rays each)
  hipLaunchKernelGGL(k_fused, dim3(16384), dim3(256), 0, stream,
                     origins, dirs, lengths, trafos, scales,
                     outL, outN, outM, outP, outD);
}